// Round 3
// baseline (450.771 us; speedup 1.0000x reference)
//
#include <hip/hip_runtime.h>
#include <hip/hip_bf16.h>

typedef __bf16 bf16x8 __attribute__((ext_vector_type(8)));
typedef float  f32x4  __attribute__((ext_vector_type(4)));

#define DEVI __device__ __forceinline__

DEVI float bf2f(__hip_bfloat16 x) { return __bfloat162float(x); }
DEVI __hip_bfloat16 f2bf(float x) { return __float2bfloat16(x); }

DEVI f32x4 mfma16(bf16x8 a, bf16x8 b, f32x4 c) {
    return __builtin_amdgcn_mfma_f32_16x16x32_bf16(a, b, c, 0, 0, 0);
}

DEVI bf16x8 ld8(const __hip_bfloat16* p) {
    return *reinterpret_cast<const bf16x8*>(p);
}

// convert 8 contiguous fp32 -> bf16x8 fragment
DEVI bf16x8 cvt8(const float* p) {
    bf16x8 r;
#pragma unroll
    for (int i = 0; i < 8; ++i) r[i] = (__bf16)p[i];
    return r;
}

// ---------------------------------------------------------------------------
// Sizes: B=64, N=256, D=128, H=8, DK=16, FF=512.  All external I/O fp32.
// ---------------------------------------------------------------------------

// K0: repack fp32 weights into MFMA-B-friendly bf16 layouts (row = out col, contiguous k)
__global__ __launch_bounds__(256) void repack_kernel(
    const float* __restrict__ Wq, const float* __restrict__ Wk,
    const float* __restrict__ Wv, const float* __restrict__ W_out,
    const float* __restrict__ ff_w1, const float* __restrict__ ff_w2,
    __hip_bfloat16* __restrict__ Wqkvt, __hip_bfloat16* __restrict__ Wot,
    __hip_bfloat16* __restrict__ w1t, __hip_bfloat16* __restrict__ w2t)
{
    int t = blockIdx.x * 256 + threadIdx.x;
    if (t < 49152) {                       // Wqkvt[c][d], c = qkv*128 + h*16 + k
        int c = t >> 7, d = t & 127;
        int qkv = c >> 7, h = (c >> 4) & 7, k = c & 15;
        const float* W = (qkv == 0) ? Wq : (qkv == 1) ? Wk : Wv;
        Wqkvt[t] = f2bf(W[(h * 128 + d) * 16 + k]);
    } else if (t < 65536) {                // Wot[d][h*16+v] = W_out[h][v][d]
        int idx = t - 49152;
        int d = idx >> 7, hv = idx & 127, h = hv >> 4, v = hv & 15;
        Wot[idx] = f2bf(W_out[(h * 16 + v) * 128 + d]);
    } else if (t < 131072) {               // w1t[f][d] = ff_w1[d][f]
        int idx = t - 65536;
        int f = idx >> 7, d = idx & 127;
        w1t[idx] = f2bf(ff_w1[d * 512 + f]);
    } else {                               // w2t[d2][f] = ff_w2[f][d2]
        int idx = t - 131072;
        int d2 = idx >> 9, f = idx & 511;
        w2t[idx] = f2bf(ff_w2[f * 128 + d2]);
    }
}

// K1: QKV projection. [16384 x 128] @ [128 x 384] -> Q [b][h][n][k], K [b][h][m][k], Vt [b][h][k][m]
__global__ __launch_bounds__(512) void qkv_kernel(
    const float* __restrict__ hem, const __hip_bfloat16* __restrict__ Wqkvt,
    __hip_bfloat16* __restrict__ Qb, __hip_bfloat16* __restrict__ Kb,
    __hip_bfloat16* __restrict__ Vtb)
{
    const int w = threadIdx.x >> 6, lane = threadIdx.x & 63;
    const int quad = lane >> 4, col = lane & 15;
    const int row0 = blockIdx.x * 32;

    f32x4 acc[2][3] = {};
#pragma unroll
    for (int ks = 0; ks < 4; ++ks) {
        bf16x8 a[2], bb[3];
#pragma unroll
        for (int mt = 0; mt < 2; ++mt)
            a[mt] = cvt8(hem + (size_t)(row0 + mt * 16 + col) * 128 + ks * 32 + quad * 8);
#pragma unroll
        for (int nt = 0; nt < 3; ++nt) {
            int c = (w * 3 + nt) * 16 + col;
            bb[nt] = ld8(Wqkvt + (size_t)c * 128 + ks * 32 + quad * 8);
        }
#pragma unroll
        for (int mt = 0; mt < 2; ++mt)
#pragma unroll
            for (int nt = 0; nt < 3; ++nt)
                acc[mt][nt] = mfma16(a[mt], bb[nt], acc[mt][nt]);
    }
#pragma unroll
    for (int mt = 0; mt < 2; ++mt)
#pragma unroll
        for (int nt = 0; nt < 3; ++nt)
#pragma unroll
            for (int rg = 0; rg < 4; ++rg) {
                int row = row0 + mt * 16 + quad * 4 + rg;
                int c = (w * 3 + nt) * 16 + col;
                int qkv = c >> 7, h = (c >> 4) & 7, k = c & 15;
                int bb_ = row >> 8, n = row & 255;
                __hip_bfloat16 v = f2bf(acc[mt][nt][rg]);
                if (qkv == 0)      Qb[(((size_t)bb_ * 8 + h) * 256 + n) * 16 + k] = v;
                else if (qkv == 1) Kb[(((size_t)bb_ * 8 + h) * 256 + n) * 16 + k] = v;
                else               Vtb[(((size_t)bb_ * 8 + h) * 16 + k) * 256 + n] = v;
            }
}

// K2: fused attention. One block = (b, 4 rows n0..n0+3). 512 threads = 8 waves.
__global__ __launch_bounds__(512) void attn_kernel_v2(
    const __hip_bfloat16* __restrict__ Qb, const __hip_bfloat16* __restrict__ Kb,
    const __hip_bfloat16* __restrict__ Vtb, const float* __restrict__ route,
    const float* __restrict__ sa_w1, const float* __restrict__ sa_b1,
    const float* __restrict__ sa_w2, const float* __restrict__ sa_b2,
    const float* __restrict__ h_em, const __hip_bfloat16* __restrict__ Wot,
    float* __restrict__ y, float* __restrict__ out)
{
    __shared__ alignas(16) __hip_bfloat16 st[1024 * 16];   // [nm][16ch] bf16; later [nm][8] f32 attn in-place
    __shared__ alignas(16) __hip_bfloat16 softb[8][4][256];
    __shared__ alignas(16) __hip_bfloat16 headsb[16][128];
    __shared__ alignas(16) __hip_bfloat16 saw1t[16][32];
    __shared__ alignas(16) __hip_bfloat16 saw2t[16][32];
    __shared__ float b1s[16], b2s[16];
    float* stf = reinterpret_cast<float*>(st);

    const int tid = threadIdx.x;
    const int w = tid >> 6, lane = tid & 63, quad = lane >> 4, col = lane & 15;
    const int b = blockIdx.x >> 6, tile = blockIdx.x & 63, n0 = tile * 4;
    const f32x4 zero = {0.f, 0.f, 0.f, 0.f};

    {   // P0: stage score_aggr weights (transposed, zero-padded to K=32)
        int o = tid >> 5, i = tid & 31;
        saw1t[o][i] = (i < 16) ? f2bf(sa_w1[i * 16 + o]) : f2bf(0.f);
        saw2t[o][i] = (i < 16 && o < 8) ? f2bf(sa_w2[i * 8 + o]) : f2bf(0.f);
        if (tid < 16) {
            b1s[tid] = sa_b1[tid];
            b2s[tid] = (tid < 8) ? sa_b2[tid] : 0.f;
        }
    }

    {   // P1: scores (wave w <-> head h=w) + route staging + route passthrough copy (fp32 exact)
        const int h = w;
        const __hip_bfloat16* Qh = Qb + ((size_t)(b * 8 + h)) * 256 * 16;
        const __hip_bfloat16* Kh = Kb + ((size_t)(b * 8 + h)) * 256 * 16;
        bf16x8 aq = ld8(Qh + (size_t)(n0 + (col & 3)) * 16 + (quad & 1) * 8);
#pragma unroll
        for (int nt = 0; nt < 16; ++nt) {
            bf16x8 bk = {};
            if (quad < 2) bk = ld8(Kh + (size_t)(nt * 16 + col) * 16 + quad * 8);
            f32x4 c = mfma16(aq, bk, zero);
            if (quad == 0) {
#pragma unroll
                for (int rg = 0; rg < 4; ++rg)
                    st[(rg * 256 + nt * 16 + col) * 16 + h] = f2bf(c[rg]);
            }
        }
        const size_t rbase = (((size_t)h * 64 + b) * 256 + n0) * 256;
        const float* rsrc = route + rbase;
        float* rdst = out + 2097152 + rbase;
#pragma unroll
        for (int r = 0; r < 4; ++r) {
            float4 rv = *(const float4*)(rsrc + r * 256 + lane * 4);
            *(float4*)(rdst + r * 256 + lane * 4) = rv;
            int nm = r * 256 + lane * 4;
            st[(nm + 0) * 16 + 8 + h] = f2bf(rv.x);
            st[(nm + 1) * 16 + 8 + h] = f2bf(rv.y);
            st[(nm + 2) * 16 + 8 + h] = f2bf(rv.z);
            st[(nm + 3) * 16 + 8 + h] = f2bf(rv.w);
        }
    }
    __syncthreads();

    {   // P2: score_aggr (2x MFMA over channel dim, in-place in st; tiles are wave-private)
        bf16x8 bw1 = *(const bf16x8*)&saw1t[col][quad * 8];
        bf16x8 bw2 = *(const bf16x8*)&saw2t[col][quad * 8];
        float bias1 = b1s[col], bias2 = b2s[col];
#pragma unroll
        for (int t8 = 0; t8 < 8; ++t8) {
            int nm0 = (w * 8 + t8) * 16;
            bf16x8 a = *(const bf16x8*)&st[(nm0 + col) * 16 + (quad & 1) * 8];
            f32x4 h1 = mfma16(a, bw1, zero);
#pragma unroll
            for (int rg = 0; rg < 4; ++rg) {
                int nm = nm0 + quad * 4 + rg;
                st[nm * 16 + col] = f2bf(fmaxf(h1[rg] + bias1, 0.f));
            }
            __asm__ volatile("s_waitcnt lgkmcnt(0)" ::: "memory");
            bf16x8 a2 = *(const bf16x8*)&st[(nm0 + col) * 16 + (quad & 1) * 8];
            f32x4 h2 = mfma16(a2, bw2, zero);
            if (col < 8) {
#pragma unroll
                for (int rg = 0; rg < 4; ++rg) {
                    int nm = nm0 + quad * 4 + rg;
                    stf[nm * 8 + col] = h2[rg] + bias2;
                }
            }
            __asm__ volatile("s_waitcnt lgkmcnt(0)" ::: "memory");
        }
    }
    __syncthreads();

    {   // P3: softmax over m for each (h, r); write soft bf16
#pragma unroll
        for (int pp = 0; pp < 4; ++pp) {
            int p = w * 4 + pp, h = p >> 2, r = p & 3;
            float vv[4];
#pragma unroll
            for (int j = 0; j < 4; ++j) vv[j] = stf[(r * 256 + j * 64 + lane) * 8 + h];
            float mx = fmaxf(fmaxf(vv[0], vv[1]), fmaxf(vv[2], vv[3]));
#pragma unroll
            for (int off = 32; off; off >>= 1) mx = fmaxf(mx, __shfl_xor(mx, off, 64));
            float e[4], s = 0.f;
#pragma unroll
            for (int j = 0; j < 4; ++j) { e[j] = __expf(vv[j] - mx); s += e[j]; }
#pragma unroll
            for (int off = 32; off; off >>= 1) s += __shfl_xor(s, off, 64);
            float inv = 1.f / s;
#pragma unroll
            for (int j = 0; j < 4; ++j) softb[h][r][j * 64 + lane] = f2bf(e[j] * inv);
        }
    }
    __syncthreads();

    {   // P4: PV (wave w <-> head h=w)
        const int h = w;
        f32x4 acc = zero;
        const __hip_bfloat16* Vh = Vtb + ((size_t)(b * 8 + h)) * 16 * 256;
#pragma unroll
        for (int ks = 0; ks < 8; ++ks) {
            bf16x8 a = *(const bf16x8*)&softb[h][col & 3][ks * 32 + quad * 8];
            bf16x8 bv = ld8(Vh + (size_t)col * 256 + ks * 32 + quad * 8);
            acc = mfma16(a, bv, acc);
        }
        if (quad == 0) {
#pragma unroll
            for (int rg = 0; rg < 4; ++rg)
                headsb[rg][h * 16 + col] = f2bf(acc[rg]);
        }
    }
    __syncthreads();

    {   // P5: out-proj + residual -> y (fp32). wave w owns d-tile [w*16, w*16+16)
        f32x4 acc = zero;
#pragma unroll
        for (int ks = 0; ks < 4; ++ks) {
            bf16x8 a = *(const bf16x8*)&headsb[col][ks * 32 + quad * 8];
            bf16x8 bo = ld8(Wot + (size_t)(w * 16 + col) * 128 + ks * 32 + quad * 8);
            acc = mfma16(a, bo, acc);
        }
        if (quad == 0) {
#pragma unroll
            for (int rg = 0; rg < 4; ++rg) {
                int n = n0 + rg, d = w * 16 + col;
                size_t idx = ((size_t)b * 256 + n) * 128 + d;
                y[idx] = acc[rg] + h_em[idx];
            }
        }
    }
}

// output store helpers for the LN template
DEVI void stout(float* p, float v) { *p = v; }
DEVI void stout(__hip_bfloat16* p, float v) { *p = f2bf(v); }

// K3/K5: per-batch LayerNorm over (n,d) = 32768 elements, unbiased var (/32767)
template<typename OUT>
__global__ __launch_bounds__(1024) void ln_kernel(
    const float* __restrict__ y, OUT* __restrict__ out)
{
    const int b = blockIdx.x;
    const float* yb = y + (size_t)b * 32768;
    float v[32], s = 0.f, sq = 0.f;
#pragma unroll
    for (int j = 0; j < 32; ++j) {
        float x = yb[threadIdx.x + 1024 * j];
        v[j] = x; s += x; sq += x * x;
    }
#pragma unroll
    for (int off = 32; off; off >>= 1) {
        s += __shfl_down(s, off, 64);
        sq += __shfl_down(sq, off, 64);
    }
    __shared__ float ps[16], pq[16], stats[2];
    int wv = threadIdx.x >> 6, ln = threadIdx.x & 63;
    if (ln == 0) { ps[wv] = s; pq[wv] = sq; }
    __syncthreads();
    if (threadIdx.x < 64) {
        float a = (ln < 16) ? ps[ln] : 0.f;
        float bq = (ln < 16) ? pq[ln] : 0.f;
#pragma unroll
        for (int off = 8; off; off >>= 1) {
            a += __shfl_down(a, off, 64);
            bq += __shfl_down(bq, off, 64);
        }
        if (ln == 0) {
            float mean = a * (1.f / 32768.f);
            float var = fmaxf((bq - 32768.f * mean * mean) * (1.f / 32767.f), 0.f);
            stats[0] = mean;
            stats[1] = rsqrtf(var + 1e-5f);
        }
    }
    __syncthreads();
    float mean = stats[0], rstd = stats[1];
    OUT* ob = out + (size_t)b * 32768;
#pragma unroll
    for (int j = 0; j < 32; ++j)
        stout(ob + threadIdx.x + 1024 * j, (v[j] - mean) * rstd);
}

// K4: fused FF: y = relu(x @ w1) @ w2 + x, hidden tile lives in LDS only
__global__ __launch_bounds__(512) void ff_kernel(
    const __hip_bfloat16* __restrict__ xb, const __hip_bfloat16* __restrict__ w1t,
    const __hip_bfloat16* __restrict__ w2t, float* __restrict__ y)
{
    __shared__ alignas(16) __hip_bfloat16 hid[64][512];   // 64 KB
    const int w = threadIdx.x >> 6, lane = threadIdx.x & 63;
    const int quad = lane >> 4, col = lane & 15;
    const int r0 = blockIdx.x * 64;

    f32x4 acc[4][4] = {};
#pragma unroll
    for (int ks = 0; ks < 4; ++ks) {
        bf16x8 a[4], bb[4];
#pragma unroll
        for (int mt = 0; mt < 4; ++mt)
            a[mt] = ld8(xb + (size_t)(r0 + mt * 16 + col) * 128 + ks * 32 + quad * 8);
#pragma unroll
        for (int nt = 0; nt < 4; ++nt) {
            int f = (w * 4 + nt) * 16 + col;
            bb[nt] = ld8(w1t + (size_t)f * 128 + ks * 32 + quad * 8);
        }
#pragma unroll
        for (int mt = 0; mt < 4; ++mt)
#pragma unroll
            for (int nt = 0; nt < 4; ++nt)
                acc[mt][nt] = mfma16(a[mt], bb[nt], acc[mt][nt]);
    }
#pragma unroll
    for (int mt = 0; mt < 4; ++mt)
#pragma unroll
        for (int nt = 0; nt < 4; ++nt)
#pragma unroll
            for (int rg = 0; rg < 4; ++rg) {
                int row = mt * 16 + quad * 4 + rg;
                int f = (w * 4 + nt) * 16 + col;
                hid[row][f] = f2bf(fmaxf(acc[mt][nt][rg], 0.f));
            }
    __syncthreads();

    f32x4 acc2[4] = {};
#pragma unroll
    for (int ks = 0; ks < 16; ++ks) {
        bf16x8 bb = ld8(w2t + (size_t)(w * 16 + col) * 512 + ks * 32 + quad * 8);
#pragma unroll
        for (int mt = 0; mt < 4; ++mt) {
            bf16x8 a = *(const bf16x8*)&hid[mt * 16 + col][ks * 32 + quad * 8];
            acc2[mt] = mfma16(a, bb, acc2[mt]);
        }
    }
#pragma unroll
    for (int mt = 0; mt < 4; ++mt)
#pragma unroll
        for (int rg = 0; rg < 4; ++rg) {
            int row = r0 + mt * 16 + quad * 4 + rg;
            int d = w * 16 + col;
            size_t idx = (size_t)row * 128 + d;
            y[idx] = acc2[mt][rg] + bf2f(xb[idx]);
        }
}

extern "C" void kernel_launch(void* const* d_in, const int* in_sizes, int n_in,
                              void* d_out, int out_size, void* d_ws, size_t ws_size,
                              hipStream_t stream)
{
    const float* h_em  = (const float*)d_in[0];
    const float* route = (const float*)d_in[1];
    const float* Wq    = (const float*)d_in[2];
    const float* Wk    = (const float*)d_in[3];
    const float* Wv    = (const float*)d_in[4];
    const float* W_out = (const float*)d_in[5];
    const float* sa_w1 = (const float*)d_in[6];
    const float* sa_b1 = (const float*)d_in[7];
    const float* sa_w2 = (const float*)d_in[8];
    const float* sa_b2 = (const float*)d_in[9];
    const float* ff_w1 = (const float*)d_in[10];
    const float* ff_w2 = (const float*)d_in[11];

    char* ws = (char*)d_ws;
    __hip_bfloat16* Qb    = (__hip_bfloat16*)(ws);
    __hip_bfloat16* Kb    = (__hip_bfloat16*)(ws + 4194304);
    __hip_bfloat16* Vtb   = (__hip_bfloat16*)(ws + 8388608);
    __hip_bfloat16* Wqkvt = (__hip_bfloat16*)(ws + 12582912);
    __hip_bfloat16* Wot   = (__hip_bfloat16*)(ws + 12681216);
    __hip_bfloat16* w1t   = (__hip_bfloat16*)(ws + 12713984);
    __hip_bfloat16* w2t   = (__hip_bfloat16*)(ws + 12845056);
    float*          yv    = (float*)(ws + 12976128);
    __hip_bfloat16* xb    = (__hip_bfloat16*)(ws + 21364736);

    hipLaunchKernelGGL(repack_kernel, dim3(768), dim3(256), 0, stream,
                       Wq, Wk, Wv, W_out, ff_w1, ff_w2, Wqkvt, Wot, w1t, w2t);
    hipLaunchKernelGGL(qkv_kernel, dim3(512), dim3(512), 0, stream,
                       h_em, Wqkvt, Qb, Kb, Vtb);
    hipLaunchKernelGGL(attn_kernel_v2, dim3(4096), dim3(512), 0, stream,
                       Qb, Kb, Vtb, route, sa_w1, sa_b1, sa_w2, sa_b2, h_em, Wot,
                       yv, (float*)d_out);
    hipLaunchKernelGGL(ln_kernel<__hip_bfloat16>, dim3(64), dim3(1024), 0, stream, yv, xb);
    hipLaunchKernelGGL(ff_kernel, dim3(256), dim3(512), 0, stream, xb, w1t, w2t, yv);
    hipLaunchKernelGGL(ln_kernel<float>, dim3(64), dim3(1024), 0, stream,
                       yv, (float*)d_out);
}